// Round 2
// baseline (140.275 us; speedup 1.0000x reference)
//
#include <hip/hip_runtime.h>
#include <hip/hip_bf16.h>
#include <stdint.h>

// cheb_conv_with_Att_static: out[b,t,v,c] = relu( sum_{k,f} theta[k,f,c] *
//     sum_u cheb[k,u,v]*Att[b,u,v]*x[b,t,u,f] )
// B=8 T=12 V=2048 F=16 K=3 C=64
#define B_  8
#define T_  12
#define V_  2048
#define F_  16
#define K_  3
#define C_  64
#define N_  192   // T*F

typedef _Float16 f16;
typedef _Float16 half4v __attribute__((ext_vector_type(4)));
typedef _Float16 half8v __attribute__((ext_vector_type(8)));
typedef float    f32x4  __attribute__((ext_vector_type(4)));
typedef float    f32x16 __attribute__((ext_vector_type(16)));
typedef unsigned int u32;

// ---------------------------------------------------------------------------
// Kernel 1: XT[b][n=t*16+f][u] = (f16) x[b][t][u][f]   (u becomes contiguous)
// ---------------------------------------------------------------------------
__global__ __launch_bounds__(256) void prep_xt(const float* __restrict__ x,
                                               f16* __restrict__ XT) {
  int bid = blockIdx.x;
  int bt = bid >> 2, uc = bid & 3;
  int b = bt / T_, t = bt % T_;
  __shared__ float tile[64][17];
  int r  = threadIdx.x >> 2, fq = threadIdx.x & 3;   // load mapping
  int f  = threadIdx.x >> 4, uq = threadIdx.x & 15;  // store mapping
  for (int u0 = uc * 512; u0 < uc * 512 + 512; u0 += 64) {
    f32x4 v = *(const f32x4*)(x + ((size_t)(b * T_ + t) * V_ + u0 + r) * F_ + fq * 4);
    tile[r][fq * 4 + 0] = v[0];
    tile[r][fq * 4 + 1] = v[1];
    tile[r][fq * 4 + 2] = v[2];
    tile[r][fq * 4 + 3] = v[3];
    __syncthreads();
    half4v h;
    h[0] = (f16)tile[uq * 4 + 0][f];
    h[1] = (f16)tile[uq * 4 + 1][f];
    h[2] = (f16)tile[uq * 4 + 2][f];
    h[3] = (f16)tile[uq * 4 + 3][f];
    *(half4v*)(XT + (size_t)(b * N_ + t * F_ + f) * V_ + u0 + uq * 4) = h;
    __syncthreads();
  }
}

// ---------------------------------------------------------------------------
// Kernel 2: per (k,b): rhs[v,(t,f)] = sum_u (cheb[k,u,v]*Att[b,u,v]) * XT[b,n,u]
// BM=64 BN=192 BK=64, 4 waves (2x2), wave tile 32x96, 32x32x16 f16 MFMA.
// Round-2: double-buffered single-barrier pipeline (T3-minimum 2-phase):
//   top of iter: issue next A-loads (f32x4 -> regs) + next B glds (alt buffer)
//   middle:      ds_read + MFMA from current buffer (setprio wrapped)
//   bottom:      product + transposed swizzled ds_write into alt buffer
//   __syncthreads (vmcnt0+lgkm0 drain = the wait we need), swap.
// XCD swizzle: b = bid&7 so the 96 blocks sharing XT[b] land on one XCD L2.
// ---------------------------------------------------------------------------
__global__ __launch_bounds__(256) void gemm_kbv(const float* __restrict__ Att,
                                                const float* __restrict__ cheb,
                                                const f16* __restrict__ XT,
                                                f16* __restrict__ rhs) {
  const int bid = blockIdx.x;
  const int b = bid & 7;            // XCD = bid % 8  -> co-locate same-b blocks
  const int r2 = bid >> 3;          // 0..95
  const int vt = r2 & 31, k = r2 >> 5;
  const int vbase = vt * 64;

  __shared__ char smem[65536];      // [2] x (A 8KB + B 24KB)

  const int tid = threadIdx.x;
  const int wave = tid >> 6, lane = tid & 63;
  const int wm = wave >> 1, wn = wave & 1;
  const int vsub = (tid & 15) * 4, usub = (tid >> 4) * 4;

  const float* cheb_base = cheb + (size_t)k * V_ * V_ + vbase + vsub + (size_t)usub * V_;
  const float* att_base  = Att  + (size_t)b * V_ * V_ + vbase + vsub + (size_t)usub * V_;
  const f16*   xt_base   = XT + (size_t)b * N_ * V_;

  f32x16 acc[3];
  acc[0] = 0; acc[1] = 0; acc[2] = 0;

  f32x4 pc[4], pa[4];

  // ---- prologue: stage tile 0 into buf0 ----
#pragma unroll
  for (int i = 0; i < 4; ++i) {
    pc[i] = *(const f32x4*)(cheb_base + (size_t)i * V_);
    pa[i] = *(const f32x4*)(att_base  + (size_t)i * V_);
  }
  {
    char* Bb = smem + 8192;
#pragma unroll
    for (int e = 0; e < 6; ++e) {
      int slot = wave * 6 + e;
      int n = slot * 8 + (lane >> 3);
      int c = (lane & 7) ^ (n & 7);
      const f16* src = xt_base + (size_t)n * V_ + c * 8;
      __builtin_amdgcn_global_load_lds((const __attribute__((address_space(1))) u32*)src,
                                       (__attribute__((address_space(3))) u32*)(Bb + slot * 1024),
                                       16, 0, 0);
    }
    char* Ab = smem;
#pragma unroll
    for (int j = 0; j < 4; ++j) {
      int vrow = vsub + j;
      half4v h;
      h[0] = (f16)(pc[0][j] * pa[0][j]); h[1] = (f16)(pc[1][j] * pa[1][j]);
      h[2] = (f16)(pc[2][j] * pa[2][j]); h[3] = (f16)(pc[3][j] * pa[3][j]);
      *(half4v*)(Ab + vrow * 128 + ((usub * 2) ^ ((vrow & 7) << 4))) = h;
    }
  }
  __syncthreads();

  int cur = 0;
  for (int t = 0; t < 32; ++t) {
    char* bufc = smem + cur * 32768;
    char* bufn = smem + (cur ^ 1) * 32768;

    // ---- issue next tile's loads (A->regs first, then B glds) ----
    if (t < 31) {
      const size_t uoff = (size_t)(t + 1) * 64 * V_;
#pragma unroll
      for (int i = 0; i < 4; ++i) {
        pc[i] = *(const f32x4*)(cheb_base + uoff + (size_t)i * V_);
        pa[i] = *(const f32x4*)(att_base  + uoff + (size_t)i * V_);
      }
      char* Bb = bufn + 8192;
#pragma unroll
      for (int e = 0; e < 6; ++e) {
        int slot = wave * 6 + e;
        int n = slot * 8 + (lane >> 3);
        int c = (lane & 7) ^ (n & 7);
        const f16* src = xt_base + (size_t)n * V_ + (t + 1) * 64 + c * 8;
        __builtin_amdgcn_global_load_lds((const __attribute__((address_space(1))) u32*)src,
                                         (__attribute__((address_space(3))) u32*)(Bb + slot * 1024),
                                         16, 0, 0);
      }
    }

    // ---- compute current buffer ----
    {
      char* Ab = bufc;
      char* Bb = bufc + 8192;
      __builtin_amdgcn_s_setprio(1);
#pragma unroll
      for (int ks = 0; ks < 4; ++ks) {
        int koff = ks * 32 + (lane >> 5) * 16;
        int vrow = wm * 32 + (lane & 31);
        half8v a = *(const half8v*)(Ab + vrow * 128 + (koff ^ ((vrow & 7) << 4)));
#pragma unroll
        for (int nf = 0; nf < 3; ++nf) {
          int nrow = wn * 96 + nf * 32 + (lane & 31);
          half8v bv = *(const half8v*)(Bb + nrow * 128 + (koff ^ ((nrow & 7) << 4)));
          acc[nf] = __builtin_amdgcn_mfma_f32_32x32x16_f16(a, bv, acc[nf], 0, 0, 0);
        }
      }
      __builtin_amdgcn_s_setprio(0);
    }

    // ---- product + transposed write into alt buffer ----
    if (t < 31) {
      char* Ab = bufn;
#pragma unroll
      for (int j = 0; j < 4; ++j) {
        int vrow = vsub + j;
        half4v h;
        h[0] = (f16)(pc[0][j] * pa[0][j]); h[1] = (f16)(pc[1][j] * pa[1][j]);
        h[2] = (f16)(pc[2][j] * pa[2][j]); h[3] = (f16)(pc[3][j] * pa[3][j]);
        *(half4v*)(Ab + vrow * 128 + ((usub * 2) ^ ((vrow & 7) << 4))) = h;
      }
    }
    __syncthreads();
    cur ^= 1;
  }

  // ---- epilogue: scatter acc -> rhs[b][t][v][k*16+f] (f16) ----
#pragma unroll
  for (int nf = 0; nf < 3; ++nf) {
    int n = wn * 96 + nf * 32 + (lane & 31);
    int t = n >> 4, fi = n & 15;
#pragma unroll
    for (int r = 0; r < 16; ++r) {
      int v = vbase + wm * 32 + (r & 3) + 8 * (r >> 2) + 4 * (lane >> 5);
      rhs[((size_t)(b * T_ + t) * V_ + v) * 48 + k * 16 + fi] = (f16)acc[nf][r];
    }
  }
}

// ---------------------------------------------------------------------------
// Kernel 3: out[row, c] = relu( sum_{kf=0..47} rhs[row][kf] * theta[kf][c] )
// ---------------------------------------------------------------------------
__global__ __launch_bounds__(256) void epi(const f16* __restrict__ rhs,
                                           const float* __restrict__ theta,
                                           float* __restrict__ out) {
  int wave = threadIdx.x >> 6, lane = threadIdx.x & 63;
  int row0 = blockIdx.x * 128 + wave * 32;
  int cl = lane & 31, kh = (lane >> 5) * 8;

  half8v bf[2][3];
#pragma unroll
  for (int nf = 0; nf < 2; ++nf)
#pragma unroll
    for (int ks = 0; ks < 3; ++ks) {
      half8v hb;
#pragma unroll
      for (int j = 0; j < 8; ++j)
        hb[j] = (f16)theta[(size_t)(ks * 16 + kh + j) * C_ + nf * 32 + cl];
      bf[nf][ks] = hb;
    }

  f32x16 acc0 = 0, acc1 = 0;
#pragma unroll
  for (int ks = 0; ks < 3; ++ks) {
    half8v a = *(const half8v*)(rhs + (size_t)(row0 + cl) * 48 + ks * 16 + kh);
    acc0 = __builtin_amdgcn_mfma_f32_32x32x16_f16(a, bf[0][ks], acc0, 0, 0, 0);
    acc1 = __builtin_amdgcn_mfma_f32_32x32x16_f16(a, bf[1][ks], acc1, 0, 0, 0);
  }
#pragma unroll
  for (int r = 0; r < 16; ++r) {
    int row = row0 + (r & 3) + 8 * (r >> 2) + 4 * (lane >> 5);
    out[(size_t)row * C_ + cl]      = fmaxf(acc0[r], 0.f);
    out[(size_t)row * C_ + 32 + cl] = fmaxf(acc1[r], 0.f);
  }
}

// ---------------------------------------------------------------------------
extern "C" void kernel_launch(void* const* d_in, const int* in_sizes, int n_in,
                              void* d_out, int out_size, void* d_ws, size_t ws_size,
                              hipStream_t stream) {
  const float* x     = (const float*)d_in[0];   // (8,12,2048,16)
  const float* Att   = (const float*)d_in[1];   // (8,2048,2048)
  const float* cheb  = (const float*)d_in[2];   // (3,2048,2048)
  const float* theta = (const float*)d_in[3];   // (3,16,64)
  float* out = (float*)d_out;                   // (8,12,2048,64) fp32

  f16* XT  = (f16*)d_ws;
  f16* rhs = (f16*)((char*)d_ws + (size_t)B_ * N_ * V_ * sizeof(f16));

  prep_xt<<<B_ * T_ * 4, 256, 0, stream>>>(x, XT);
  gemm_kbv<<<K_ * B_ * 32, 256, 0, stream>>>(Att, cheb, XT, rhs);
  epi<<<(B_ * T_ * V_) / 128, 256, 0, stream>>>(rhs, theta, out);
}

// Round 3
// 107.161 us; speedup vs baseline: 1.3090x; 1.3090x over previous
//
#include <hip/hip_runtime.h>
#include <hip/hip_bf16.h>
#include <stdint.h>

// cheb_conv_with_Att_static: out[b,t,v,c] = relu( sum_{k,f} theta[k,f,c] *
//     sum_u cheb[k,u,v]*Att[b,u,v]*x[b,t,u,f] )
// B=8 T=12 V=2048 F=16 K=3 C=64
#define B_  8
#define T_  12
#define V_  2048
#define F_  16
#define K_  3
#define C_  64
#define N_  192   // T*F

typedef _Float16 f16;
typedef _Float16 half4v __attribute__((ext_vector_type(4)));
typedef _Float16 half8v __attribute__((ext_vector_type(8)));
typedef float    f32x4  __attribute__((ext_vector_type(4)));
typedef float    f32x16 __attribute__((ext_vector_type(16)));
typedef unsigned int u32;

// ---------------------------------------------------------------------------
// Kernel 1: XT[b][n=t*16+f][u] = (f16) x[b][t][u][f]   (u becomes contiguous)
// ---------------------------------------------------------------------------
__global__ __launch_bounds__(256) void prep_xt(const float* __restrict__ x,
                                               f16* __restrict__ XT) {
  int bid = blockIdx.x;
  int bt = bid >> 2, uc = bid & 3;
  int b = bt / T_, t = bt % T_;
  __shared__ float tile[64][17];
  int r  = threadIdx.x >> 2, fq = threadIdx.x & 3;   // load mapping
  int f  = threadIdx.x >> 4, uq = threadIdx.x & 15;  // store mapping
  for (int u0 = uc * 512; u0 < uc * 512 + 512; u0 += 64) {
    f32x4 v = *(const f32x4*)(x + ((size_t)(b * T_ + t) * V_ + u0 + r) * F_ + fq * 4);
    tile[r][fq * 4 + 0] = v[0];
    tile[r][fq * 4 + 1] = v[1];
    tile[r][fq * 4 + 2] = v[2];
    tile[r][fq * 4 + 3] = v[3];
    __syncthreads();
    half4v h;
    h[0] = (f16)tile[uq * 4 + 0][f];
    h[1] = (f16)tile[uq * 4 + 1][f];
    h[2] = (f16)tile[uq * 4 + 2][f];
    h[3] = (f16)tile[uq * 4 + 3][f];
    *(half4v*)(XT + (size_t)(b * N_ + t * F_ + f) * V_ + u0 + uq * 4) = h;
    __syncthreads();
  }
}

// ---------------------------------------------------------------------------
// Kernel 2 (k-fused, u-split): per (b,vt,uh): for all 3 k simultaneously,
//   rhs[b][t][v][uh*48 + k*16 + f] = sum_{u in uh-half} (cheb[k,u,v]*Att[b,u,v]) * XT[b,n,u]
// BM=64, BN=192, BK=64, 4 waves (2x2), wave tile 32x96, 32x32x16 f16 MFMA.
// Single 48KB buffer (2 blocks/CU co-resident), reg-staged prefetch:
//   loads(t+1) issue at compute(t) top -> f16 products mid-compute ->
//   barrier -> glds B(t+1) + ds_write A-products -> barrier.
// Swizzles: A rows 128B, elem (v,u) at v*128 + ((u*2)^(((v>>2)&7)<<4))
//   (write key (v>>2)&7 varies across lanes per store -> b64 floor; frag
//    reads conflict-free). B rows 128B, key (n&7) via pre-swizzled glds src.
// XCD: bid%8 = (2vt+uh)%8 -> the 8 b-blocks sharing a cheb slice co-locate.
// ---------------------------------------------------------------------------
template<int UH>
__global__ __launch_bounds__(256, 2) void gemm_fused(const float* __restrict__ Att,
                                                     const float* __restrict__ cheb,
                                                     const f16* __restrict__ XT,
                                                     f16* __restrict__ rhs) {
  constexpr int NSTEP = (V_ / UH) / 64;
  const int bid = blockIdx.x;
  const int b  = bid / (32 * UH);
  const int rr = bid % (32 * UH);
  const int vt = rr / UH, uh = rr % UH;
  const int vbase = vt * 64;
  const size_t ubase = (size_t)uh * (V_ / UH);

  __shared__ char smem[49152];
  char* Ab = smem;            // 3 x 8KB  (k-major)
  char* Bb = smem + 24576;    // 24KB

  const int tid = threadIdx.x;
  const int wave = tid >> 6, lane = tid & 63;
  const int wm = wave >> 1, wn = wave & 1;
  const int vsub = (tid & 15) * 4, usub = (tid >> 4) * 4;

  const float* attb  = Att + (size_t)b * V_ * V_ + vbase + vsub + (size_t)usub * V_;
  const float* chebb = cheb + vbase + vsub + (size_t)usub * V_;   // +k*V*V +u*V
  const f16*   xtb   = XT + (size_t)b * N_ * V_;

  f32x16 acc[3][3];
#pragma unroll
  for (int k = 0; k < 3; ++k)
#pragma unroll
    for (int nf = 0; nf < 3; ++nf) acc[k][nf] = 0;

  const int vrow = wm * 32 + (lane & 31);
  const int akey = ((vrow >> 2) & 7) << 4;
  int nrowA[3], bkeyA[3];
#pragma unroll
  for (int nf = 0; nf < 3; ++nf) {
    nrowA[nf] = wn * 96 + nf * 32 + (lane & 31);
    bkeyA[nf] = (nrowA[nf] & 7) << 4;
  }
  const int wkey = (tid & 7) << 4;       // == ((vsub+j)>>2 & 7)<<4 for j<4
  const int gl_c = (lane & 7) ^ (lane >> 3);  // pre-swizzled src chunk

  // glds B tile at u-offset `u` into Bb (linear dest, swizzled src)
  auto stageB = [&](size_t u) {
#pragma unroll
    for (int e = 0; e < 6; ++e) {
      int slot = wave * 6 + e;
      int n = slot * 8 + (lane >> 3);
      const f16* src = xtb + (size_t)n * V_ + u + gl_c * 8;
      __builtin_amdgcn_global_load_lds((const __attribute__((address_space(1))) u32*)src,
                                       (__attribute__((address_space(3))) u32*)(Bb + slot * 1024),
                                       16, 0, 0);
    }
  };
  // write staged products into A buffers
  auto writeA = [&](half4v pk[3][4]) {
#pragma unroll
    for (int k = 0; k < 3; ++k)
#pragma unroll
      for (int j = 0; j < 4; ++j)
        *(half4v*)(Ab + k * 8192 + (vsub + j) * 128 + ((usub * 2) ^ wkey)) = pk[k][j];
  };

  // ---- prologue: stage step 0 ----
  {
    f32x4 pa[4], cv[3][4];
#pragma unroll
    for (int i = 0; i < 4; ++i) pa[i] = *(const f32x4*)(attb + (ubase + i) * V_);
#pragma unroll
    for (int k = 0; k < 3; ++k)
#pragma unroll
      for (int i = 0; i < 4; ++i)
        cv[k][i] = *(const f32x4*)(chebb + (size_t)k * V_ * V_ + (ubase + i) * V_);
    stageB(ubase);
    half4v pk[3][4];
#pragma unroll
    for (int k = 0; k < 3; ++k)
#pragma unroll
      for (int j = 0; j < 4; ++j) {
        half4v h;
        h[0] = (f16)(cv[k][0][j] * pa[0][j]); h[1] = (f16)(cv[k][1][j] * pa[1][j]);
        h[2] = (f16)(cv[k][2][j] * pa[2][j]); h[3] = (f16)(cv[k][3][j] * pa[3][j]);
        pk[k][j] = h;
      }
    writeA(pk);
    __syncthreads();
  }

#define COMPUTE_KS(ks)                                                          \
  {                                                                             \
    const int ku2 = (ks) * 32 + (lane >> 5) * 16;                               \
    half8v bfr0 = *(const half8v*)(Bb + nrowA[0] * 128 + (ku2 ^ bkeyA[0]));     \
    half8v bfr1 = *(const half8v*)(Bb + nrowA[1] * 128 + (ku2 ^ bkeyA[1]));     \
    half8v bfr2 = *(const half8v*)(Bb + nrowA[2] * 128 + (ku2 ^ bkeyA[2]));     \
    __builtin_amdgcn_s_setprio(1);                                              \
    _Pragma("unroll")                                                           \
    for (int k = 0; k < 3; ++k) {                                               \
      half8v a = *(const half8v*)(Ab + k * 8192 + vrow * 128 + (ku2 ^ akey));   \
      acc[k][0] = __builtin_amdgcn_mfma_f32_32x32x16_f16(a, bfr0, acc[k][0], 0, 0, 0); \
      acc[k][1] = __builtin_amdgcn_mfma_f32_32x32x16_f16(a, bfr1, acc[k][1], 0, 0, 0); \
      acc[k][2] = __builtin_amdgcn_mfma_f32_32x32x16_f16(a, bfr2, acc[k][2], 0, 0, 0); \
    }                                                                           \
    __builtin_amdgcn_s_setprio(0);                                              \
  }

  for (int t = 0; t < NSTEP; ++t) {
    const bool pref = (t + 1) < NSTEP;
    const size_t unext = ubase + (size_t)(t + 1) * 64;
    f32x4 pa[4], cv[3][4];
    half4v pk[3][4];

    if (pref) {
#pragma unroll
      for (int i = 0; i < 4; ++i) pa[i] = *(const f32x4*)(attb + (unext + i) * V_);
#pragma unroll
      for (int k = 0; k < 3; ++k)
#pragma unroll
        for (int i = 0; i < 4; ++i)
          cv[k][i] = *(const f32x4*)(chebb + (size_t)k * V_ * V_ + (unext + i) * V_);
    }

    COMPUTE_KS(0)
    COMPUTE_KS(1)

    if (pref) {
#pragma unroll
      for (int k = 0; k < 3; ++k)
#pragma unroll
        for (int j = 0; j < 4; ++j) {
          half4v h;
          h[0] = (f16)(cv[k][0][j] * pa[0][j]); h[1] = (f16)(cv[k][1][j] * pa[1][j]);
          h[2] = (f16)(cv[k][2][j] * pa[2][j]); h[3] = (f16)(cv[k][3][j] * pa[3][j]);
          pk[k][j] = h;
        }
    }

    COMPUTE_KS(2)
    COMPUTE_KS(3)

    __syncthreads();
    if (pref) {
      stageB(unext);
      writeA(pk);
      __syncthreads();
    }
  }
#undef COMPUTE_KS

  // ---- epilogue: scatter acc -> rhs[b][t][v][uh*48 + k*16 + f] (f16) ----
#pragma unroll
  for (int nf = 0; nf < 3; ++nf) {
    int n = wn * 96 + nf * 32 + (lane & 31);
    int tt = n >> 4, fi = n & 15;
#pragma unroll
    for (int k = 0; k < 3; ++k) {
#pragma unroll
      for (int r = 0; r < 16; ++r) {
        int v = vbase + wm * 32 + (r & 3) + 8 * (r >> 2) + 4 * (lane >> 5);
        rhs[((size_t)(b * T_ + tt) * V_ + v) * (48 * UH) + uh * 48 + k * 16 + fi] =
            (f16)acc[k][nf][r];
      }
    }
  }
}

// ---------------------------------------------------------------------------
// Kernel 3: out[row, c] = relu( sum_{s=0..3*UH-1} rhs[row][s*16+..] * theta[(s%3)*16+..][c] )
// (uh halves of rhs share the same theta -> reuse B-frags via s%3)
// ---------------------------------------------------------------------------
template<int UH>
__global__ __launch_bounds__(256) void epi(const f16* __restrict__ rhs,
                                           const float* __restrict__ theta,
                                           float* __restrict__ out) {
  int wave = threadIdx.x >> 6, lane = threadIdx.x & 63;
  int row0 = blockIdx.x * 128 + wave * 32;
  int cl = lane & 31, kh = (lane >> 5) * 8;

  half8v bf[2][3];
#pragma unroll
  for (int nf = 0; nf < 2; ++nf)
#pragma unroll
    for (int ks = 0; ks < 3; ++ks) {
      half8v hb;
#pragma unroll
      for (int j = 0; j < 8; ++j)
        hb[j] = (f16)theta[(size_t)(ks * 16 + kh + j) * C_ + nf * 32 + cl];
      bf[nf][ks] = hb;
    }

  f32x16 acc0 = 0, acc1 = 0;
#pragma unroll
  for (int s = 0; s < 3 * UH; ++s) {
    half8v a = *(const half8v*)(rhs + (size_t)(row0 + cl) * (48 * UH) + s * 16 + kh);
    acc0 = __builtin_amdgcn_mfma_f32_32x32x16_f16(a, bf[0][s % 3], acc0, 0, 0, 0);
    acc1 = __builtin_amdgcn_mfma_f32_32x32x16_f16(a, bf[1][s % 3], acc1, 0, 0, 0);
  }
#pragma unroll
  for (int r = 0; r < 16; ++r) {
    int row = row0 + (r & 3) + 8 * (r >> 2) + 4 * (lane >> 5);
    out[(size_t)row * C_ + cl]      = fmaxf(acc0[r], 0.f);
    out[(size_t)row * C_ + 32 + cl] = fmaxf(acc1[r], 0.f);
  }
}

// ---------------------------------------------------------------------------
extern "C" void kernel_launch(void* const* d_in, const int* in_sizes, int n_in,
                              void* d_out, int out_size, void* d_ws, size_t ws_size,
                              hipStream_t stream) {
  const float* x     = (const float*)d_in[0];   // (8,12,2048,16)
  const float* Att   = (const float*)d_in[1];   // (8,2048,2048)
  const float* cheb  = (const float*)d_in[2];   // (3,2048,2048)
  const float* theta = (const float*)d_in[3];   // (3,16,64)
  float* out = (float*)d_out;                   // (8,12,2048,64) fp32

  const size_t xtB   = (size_t)B_ * N_ * V_ * sizeof(f16);          // 6.3 MB
  const size_t rhsB2 = (size_t)B_ * T_ * V_ * 96 * sizeof(f16);     // 37.7 MB

  f16* XT  = (f16*)d_ws;
  f16* rhs = (f16*)((char*)d_ws + xtB);

  prep_xt<<<B_ * T_ * 4, 256, 0, stream>>>(x, XT);
  if (ws_size >= xtB + rhsB2) {
    gemm_fused<2><<<B_ * 32 * 2, 256, 0, stream>>>(Att, cheb, XT, rhs);
    epi<2><<<(B_ * T_ * V_) / 128, 256, 0, stream>>>(rhs, theta, out);
  } else {
    gemm_fused<1><<<B_ * 32, 256, 0, stream>>>(Att, cheb, XT, rhs);
    epi<1><<<(B_ * T_ * V_) / 128, 256, 0, stream>>>(rhs, theta, out);
  }
}